// Round 5
// baseline (14007.996 us; speedup 1.0000x reference)
//
#include <hip/hip_runtime.h>

#define D 64
#define EPS 1e-12f

// bucket = row >> SB  (64 rows per bucket)
#define SB 6
#define BSZ (1 << SB)
#define NBMAX 2048        // max buckets -> supports nrows <= 131072
#define NCHUNK 128        // edge chunks for the partition

__device__ __forceinline__ float wave_sum(float v) {
#pragma unroll
  for (int off = 32; off > 0; off >>= 1) v += __shfl_xor(v, off, 64);
  return v;
}

// v[d] = sum_j att_mat[d, j] * att_agg[j]
__global__ void compute_v_kernel(const float* __restrict__ att_mat,
                                 const float* __restrict__ att_agg,
                                 float* __restrict__ v) {
  int d = threadIdx.x;
  float s = 0.f;
#pragma unroll
  for (int j = 0; j < D; ++j) s += att_mat[d * D + j] * att_agg[j];
  v[d] = s;
}

// u_k = emb * sigmoid(emb @ W_k + b_k) for k=0..3.
// W channel-interleaved in LDS as float4[j][lane]; row-blocked R=4.
__global__ __launch_bounds__(256) void gating4_kernel(
    const float* __restrict__ emb, const float* __restrict__ W,
    const float* __restrict__ B, float* __restrict__ u0, float* __restrict__ u1,
    float* __restrict__ u2, float* __restrict__ u3, float* __restrict__ a0,
    float* __restrict__ a1, float* __restrict__ a2, float* __restrict__ a3,
    int nrows) {
  __shared__ float4 sW4[D * D];  // 64 KiB
  for (int i = threadIdx.x; i < D * D; i += blockDim.x)
    sW4[i] = make_float4(W[i], W[D * D + i], W[2 * D * D + i],
                         W[3 * D * D + i]);
  __syncthreads();
  int lane = threadIdx.x & 63;
  int wid = (blockIdx.x * blockDim.x + threadIdx.x) >> 6;
  int nw = (gridDim.x * blockDim.x) >> 6;
  float b0 = B[0 * D + lane], b1 = B[1 * D + lane];
  float b2 = B[2 * D + lane], b3 = B[3 * D + lane];
  for (int r0 = wid * 4; r0 < nrows; r0 += nw * 4) {
    float e[4];
    float y[4][4];
#pragma unroll
    for (int i = 0; i < 4; ++i) {
      int r = r0 + i < nrows ? r0 + i : r0;
      e[i] = emb[(size_t)r * D + lane];
      y[i][0] = b0; y[i][1] = b1; y[i][2] = b2; y[i][3] = b3;
    }
#pragma unroll 16
    for (int j = 0; j < D; ++j) {
      float4 w = sW4[j * D + lane];
#pragma unroll
      for (int i = 0; i < 4; ++i) {
        float ej = __shfl(e[i], j, 64);
        y[i][0] += ej * w.x;
        y[i][1] += ej * w.y;
        y[i][2] += ej * w.z;
        y[i][3] += ej * w.w;
      }
    }
#pragma unroll
    for (int i = 0; i < 4; ++i) {
      int r = r0 + i;
      if (r < nrows) {
        size_t idx = (size_t)r * D + lane;
        float o0 = e[i] / (1.f + __expf(-y[i][0]));
        float o1 = e[i] / (1.f + __expf(-y[i][1]));
        float o2 = e[i] / (1.f + __expf(-y[i][2]));
        float o3 = e[i] / (1.f + __expf(-y[i][3]));
        u0[idx] = o0; u1[idx] = o1; u2[idx] = o2; u3[idx] = o3;
        if (a0) { a0[idx] = o0; a1[idx] = o1; a2[idx] = o2; a3[idx] = o3; }
      }
    }
  }
}

// sg_k = x * sigmoid(x @ W_k + b_k) for k=0..2 (same structure as gating4)
__global__ __launch_bounds__(256) void sgating3_kernel(
    const float* __restrict__ x, const float* __restrict__ W,
    const float* __restrict__ B, float* __restrict__ o0f,
    float* __restrict__ o1f, float* __restrict__ o2f, int nrows) {
  __shared__ float4 sW4[D * D];
  for (int i = threadIdx.x; i < D * D; i += blockDim.x)
    sW4[i] = make_float4(W[i], W[D * D + i], W[2 * D * D + i], 0.f);
  __syncthreads();
  int lane = threadIdx.x & 63;
  int wid = (blockIdx.x * blockDim.x + threadIdx.x) >> 6;
  int nw = (gridDim.x * blockDim.x) >> 6;
  float b0 = B[0 * D + lane], b1 = B[1 * D + lane], b2 = B[2 * D + lane];
  for (int r0 = wid * 4; r0 < nrows; r0 += nw * 4) {
    float e[4];
    float y[4][3];
#pragma unroll
    for (int i = 0; i < 4; ++i) {
      int r = r0 + i < nrows ? r0 + i : r0;
      e[i] = x[(size_t)r * D + lane];
      y[i][0] = b0; y[i][1] = b1; y[i][2] = b2;
    }
#pragma unroll 16
    for (int j = 0; j < D; ++j) {
      float4 w = sW4[j * D + lane];
#pragma unroll
      for (int i = 0; i < 4; ++i) {
        float ej = __shfl(e[i], j, 64);
        y[i][0] += ej * w.x;
        y[i][1] += ej * w.y;
        y[i][2] += ej * w.z;
      }
    }
#pragma unroll
    for (int i = 0; i < 4; ++i) {
      int r = r0 + i;
      if (r < nrows) {
        size_t idx = (size_t)r * D + lane;
        o0f[idx] = e[i] / (1.f + __expf(-y[i][0]));
        o1f[idx] = e[i] / (1.f + __expf(-y[i][1]));
        o2f[idx] = e[i] / (1.f + __expf(-y[i][2]));
      }
    }
  }
}

// mixed = (softmax-weighted(u0,u1,u2) + us) * 0.5
__global__ __launch_bounds__(256) void attn_mix_kernel(
    const float* __restrict__ u0, const float* __restrict__ u1,
    const float* __restrict__ u2, const float* __restrict__ us,
    const float* __restrict__ v, float* __restrict__ mixed, int nrows) {
  int lane = threadIdx.x & 63;
  int wid = (blockIdx.x * blockDim.x + threadIdx.x) >> 6;
  if (wid >= nrows) return;
  int idx = wid * D + lane;
  float e0 = u0[idx], e1 = u1[idx], e2 = u2[idx], eu = us[idx];
  float vd = v[lane];
  float w0 = wave_sum(e0 * vd);
  float w1 = wave_sum(e1 * vd);
  float w2 = wave_sum(e2 * vd);
  float m = fmaxf(w0, fmaxf(w1, w2));
  float s0 = __expf(w0 - m), s1 = __expf(w1 - m), s2 = __expf(w2 - m);
  float inv = 1.f / (s0 + s1 + s2);
  mixed[idx] = ((s0 * e0 + s1 * e1 + s2 * e2) * inv + eu) * 0.5f;
}

// out = softmax-weighted(a0,a1,a2) + 0.5*as  (as may alias out; per-element safe)
__global__ __launch_bounds__(256) void final_attn_kernel(
    const float* __restrict__ a0, const float* __restrict__ a1,
    const float* __restrict__ a2, const float* __restrict__ as,
    const float* __restrict__ v, float* __restrict__ out, int nrows) {
  int lane = threadIdx.x & 63;
  int wid = (blockIdx.x * blockDim.x + threadIdx.x) >> 6;
  if (wid >= nrows) return;
  int idx = wid * D + lane;
  float e0 = a0[idx], e1 = a1[idx], e2 = a2[idx], eu = as[idx];
  float vd = v[lane];
  float w0 = wave_sum(e0 * vd);
  float w1 = wave_sum(e1 * vd);
  float w2 = wave_sum(e2 * vd);
  float m = fmaxf(w0, fmaxf(w1, w2));
  float s0 = __expf(w0 - m), s1 = __expf(w1 - m), s2 = __expf(w2 - m);
  float inv = 1.f / (s0 + s1 + s2);
  out[idx] = (s0 * e0 + s1 * e1 + s2 * e2) * inv + 0.5f * eu;
}

// acc += x / max(||x_row||, eps)   (fallback path only)
__global__ __launch_bounds__(256) void l2acc_kernel(const float* __restrict__ x,
                                                    float* __restrict__ acc,
                                                    int nrows) {
  int lane = threadIdx.x & 63;
  int wid = (blockIdx.x * blockDim.x + threadIdx.x) >> 6;
  if (wid >= nrows) return;
  int idx = wid * D + lane;
  float xv = x[idx];
  float ss = wave_sum(xv * xv);
  float nrm = fmaxf(sqrtf(ss), EPS);
  acc[idx] += xv / nrm;
}

// out[row[e], :] += val[e] * x[col[e], :]  (fallback atomic scatter)
__global__ __launch_bounds__(256) void spmm_atomic_kernel(
    const int* __restrict__ row, const int* __restrict__ col,
    const float* __restrict__ val, const float* __restrict__ x,
    float* __restrict__ out, int nnz) {
  int lane = threadIdx.x & 63;
  int wid = (blockIdx.x * blockDim.x + threadIdx.x) >> 6;
  int nw = (gridDim.x * blockDim.x) >> 6;
  for (int base = wid * 64; base < nnz; base += nw * 64) {
    int e = base + lane;
    int r = 0, c = 0;
    float v = 0.f;
    if (e < nnz) { r = row[e]; c = col[e]; v = val[e]; }
    int cnt = nnz - base; if (cnt > 64) cnt = 64;
    for (int i = 0; i < cnt; ++i) {
      int ri = __shfl(r, i, 64);
      int ci = __shfl(c, i, 64);
      float vi = __shfl(v, i, 64);
      float xv = x[ci * D + lane];
      atomicAdd(&out[ri * D + lane], vi * xv);
    }
  }
}

// ---------------- bucket-grouped edge build (chunk-major) ----------------
// Pass 1: per-chunk bucket histogram -> bh[k*nb + b].
__global__ __launch_bounds__(256) void bhist_kernel(
    const int* __restrict__ row, int* __restrict__ bh, int nnz, int nb,
    int chunk) {
  __shared__ int hist[NBMAX];
  for (int i = threadIdx.x; i < nb; i += blockDim.x) hist[i] = 0;
  __syncthreads();
  int base = blockIdx.x * chunk;
  int lim = base + chunk;
  if (lim > nnz) lim = nnz;
  for (int e = base + threadIdx.x; e < lim; e += blockDim.x)
    atomicAdd(&hist[row[e] >> SB], 1);
  __syncthreads();
  int* o = bh + (size_t)blockIdx.x * nb;
  for (int i = threadIdx.x; i < nb; i += blockDim.x) o[i] = hist[i];
}

// Pass 2: per-chunk exclusive scan of its nb counts ->
// fo[k*(nb+1)+b] = k*chunk + excl_prefix ; fo[k*(nb+1)+nb] = chunk end.
// Each chunk's output region is exactly its input range (permutation).
__global__ __launch_bounds__(256) void chunkscan_kernel(
    const int* __restrict__ bh, int* __restrict__ fo, int nnz, int nb,
    int chunk) {
  __shared__ int lds[256];
  int k = blockIdx.x;
  int base = k * chunk;
  int t = threadIdx.x;
  const int* in = bh + (size_t)k * nb;
  int v[8];
  int s = 0;
#pragma unroll
  for (int q = 0; q < 8; ++q) {
    int b = t * 8 + q;
    v[q] = (b < nb) ? in[b] : 0;
    s += v[q];
  }
  lds[t] = s;
  __syncthreads();
  for (int ofs = 1; ofs < 256; ofs <<= 1) {
    int add = 0;
    if (t >= ofs) add = lds[t - ofs];
    __syncthreads();
    if (t >= ofs) lds[t] += add;
    __syncthreads();
  }
  int run = base + lds[t] - s;
  int* o = fo + (size_t)k * (nb + 1);
#pragma unroll
  for (int q = 0; q < 8; ++q) {
    int b = t * 8 + q;
    if (b < nb) o[b] = run;
    run += v[q];
  }
  if (t == 255) o[nb] = run;  // = base + edges-in-chunk
}

// Pass 3: scatter edges bucket-grouped WITHIN the block's own contiguous
// region [k*chunk, k*chunk+cnt). Every staging line is written by exactly
// one block (one XCD) over a ~200 KB L2-resident window -> full-line
// writebacks, compulsory-only HBM write traffic. (The old bucket-major
// layout shared boundary lines across XCDs: 86 MB writes for a 25.6 MB
// payload and 146 us.) lrow (6 bits) packed into col's high bits.
__global__ __launch_bounds__(256) void bscatter2_kernel(
    const int* __restrict__ row, const int* __restrict__ col,
    const float* __restrict__ val, const int* __restrict__ fo,
    int2* __restrict__ staging, int nnz, int nb, int chunk) {
  __shared__ int cur[NBMAX];
  const int* o = fo + (size_t)blockIdx.x * (nb + 1);
  for (int i = threadIdx.x; i < nb; i += blockDim.x) cur[i] = o[i];
  __syncthreads();
  int base = blockIdx.x * chunk;
  int lim = base + chunk;
  if (lim > nnz) lim = nnz;
  for (int e = base + threadIdx.x; e < lim; e += blockDim.x) {
    int r = row[e];
    int b = r >> SB;
    int idx = atomicAdd(&cur[b], 1);
    staging[idx] =
        make_int2(((r & (BSZ - 1)) << 24) | col[e], __float_as_int(val[e]));
  }
}

// ---------------- bucket-block fused SpMM + l2norm-accumulate ----------
// One block per 64-row bucket. Edges for bucket b live in NCHUNK fragments
// [fo[k][b], fo[k][b+1]). Accumulate into a 16 KB LDS tile via ds_add_f32
// (bank = lane -> conflict-free), then per-row l2norm + acc in-block.
// acc[r,:] = (init ? init[r,:] : acc[r,:]) + out[r,:]/max(||out[r,:]||,eps)
__global__ __launch_bounds__(256) void spmm_bucket_l2acc_kernel(
    const int* __restrict__ fo, const int2* __restrict__ staging,
    const float* __restrict__ x, float* __restrict__ out,
    float* __restrict__ acc, const float* __restrict__ init, int nrows,
    int nb) {
  __shared__ float sacc[BSZ * D];  // 16 KiB
  int b = blockIdx.x;
  int t = threadIdx.x;
  int lane = t & 63;
  int w = t >> 6;  // 4 waves
  for (int i = t; i < BSZ * D / 4; i += blockDim.x)
    ((float4*)sacc)[i] = make_float4(0.f, 0.f, 0.f, 0.f);
  __syncthreads();
  for (int k = w; k < NCHUNK; k += 4) {
    const int* o = fo + (size_t)k * (nb + 1) + b;
    int fs = o[0], fe = o[1];
    for (int j = fs; j < fe; j += 64) {
      int e = j + lane;
      int cw = 0;
      float v = 0.f;
      if (e < fe) {
        int2 ev = staging[e];
        cw = ev.x;
        v = __int_as_float(ev.y);
      }
      int cnt = fe - j;
      if (cnt > 64) cnt = 64;
      int i = 0;
      for (; i + 4 <= cnt; i += 4) {
        int s0 = __shfl(cw, i, 64);
        int s1 = __shfl(cw, i + 1, 64);
        int s2 = __shfl(cw, i + 2, 64);
        int s3 = __shfl(cw, i + 3, 64);
        float v0 = __shfl(v, i, 64);
        float v1 = __shfl(v, i + 1, 64);
        float v2 = __shfl(v, i + 2, 64);
        float v3 = __shfl(v, i + 3, 64);
        float x0 = x[(s0 & 0xFFFFFF) * D + lane];
        float x1 = x[(s1 & 0xFFFFFF) * D + lane];
        float x2 = x[(s2 & 0xFFFFFF) * D + lane];
        float x3 = x[(s3 & 0xFFFFFF) * D + lane];
        atomicAdd(&sacc[(((unsigned)s0) >> 24) * D + lane], v0 * x0);
        atomicAdd(&sacc[(((unsigned)s1) >> 24) * D + lane], v1 * x1);
        atomicAdd(&sacc[(((unsigned)s2) >> 24) * D + lane], v2 * x2);
        atomicAdd(&sacc[(((unsigned)s3) >> 24) * D + lane], v3 * x3);
      }
      for (; i < cnt; ++i) {
        int si = __shfl(cw, i, 64);
        float vi = __shfl(v, i, 64);
        float xv = x[(si & 0xFFFFFF) * D + lane];
        atomicAdd(&sacc[(((unsigned)si) >> 24) * D + lane], vi * xv);
      }
    }
  }
  __syncthreads();
  for (int lr = w; lr < BSZ; lr += 4) {
    int r = (b << SB) + lr;
    if (r >= nrows) break;
    float sum = sacc[lr * D + lane];
    float ss = wave_sum(sum * sum);
    float nrm = fmaxf(sqrtf(ss), EPS);
    size_t idx = (size_t)r * D + lane;
    out[idx] = sum;
    float bb = init ? init[idx] : acc[idx];
    acc[idx] = bb + sum / nrm;
  }
}

// ---------------- host ----------------

static void build_buckets(const int* row, const int* col, const float* val,
                          int nnz, int nrows, int* bh, int* fo, int2* staging,
                          hipStream_t stream) {
  int nb = (nrows + BSZ - 1) >> SB;
  int chunk = (nnz + NCHUNK - 1) / NCHUNK;
  hipLaunchKernelGGL(bhist_kernel, dim3(NCHUNK), dim3(256), 0, stream, row, bh,
                     nnz, nb, chunk);
  hipLaunchKernelGGL(chunkscan_kernel, dim3(NCHUNK), dim3(256), 0, stream, bh,
                     fo, nnz, nb, chunk);
  hipLaunchKernelGGL(bscatter2_kernel, dim3(NCHUNK), dim3(256), 0, stream, row,
                     col, val, fo, staging, nnz, nb, chunk);
}

extern "C" void kernel_launch(void* const* d_in, const int* in_sizes, int n_in,
                              void* d_out, int out_size, void* d_ws,
                              size_t ws_size, hipStream_t stream) {
  const float* user_emb = (const float*)d_in[0];
  const float* item_emb = (const float*)d_in[1];
  const float* gating_w = (const float*)d_in[2];
  const float* gating_b = (const float*)d_in[3];
  const float* sgating_w = (const float*)d_in[4];
  const float* sgating_b = (const float*)d_in[5];
  const float* att_mat = (const float*)d_in[6];
  const float* att_agg = (const float*)d_in[7];
  const int* hs_row = (const int*)d_in[8];
  const int* hs_col = (const int*)d_in[9];
  const float* hs_val = (const float*)d_in[10];
  const int* hj_row = (const int*)d_in[11];
  const int* hj_col = (const int*)d_in[12];
  const float* hj_val = (const float*)d_in[13];
  const int* hp_row = (const int*)d_in[14];
  const int* hp_col = (const int*)d_in[15];
  const float* hp_val = (const float*)d_in[16];
  const int* inter_row = (const int*)d_in[17];
  const int* inter_col = (const int*)d_in[18];
  const float* inter_val = (const float*)d_in[19];

  const int U = in_sizes[0] / D;  // 100000
  const int I = in_sizes[1] / D;  // 50000
  const int NH = in_sizes[8];     // 3200000
  const int NI = in_sizes[17];    // 3000000
  const size_t UD = (size_t)U * D;
  const size_t ID = (size_t)I * D;

  float* out = (float*)d_out;
  float* final_user = out;  // also acc_simple storage
  float* acc_item = out + UD;
  float* sg0 = out + UD + ID;  // also acc_c0
  float* sg1 = sg0 + UD;       // also acc_c1
  float* sg2 = sg1 + UD;       // also acc_c2
  float* acc0 = sg0, *acc1 = sg1, *acc2 = sg2, *accS = final_user;

  // ---- workspace bump allocator ----
  char* p = (char*)d_ws;
  auto alloc = [&](size_t bytes) -> void* {
    void* r = (void*)p;
    p += (bytes + 255) & ~(size_t)255;
    return r;
  };
  float* u0 = (float*)alloc(UD * 4);
  float* u1 = (float*)alloc(UD * 4);
  float* u2 = (float*)alloc(UD * 4);
  float* us = (float*)alloc(UD * 4);
  float* mixed = (float*)alloc(UD * 4);
  float* spare = (float*)alloc(UD * 4);
  float* it_a = (float*)alloc(ID * 4);
  float* it_b = (float*)alloc(ID * 4);
  float* v = (float*)alloc(256 * 4);
  // bucket structures
  int* bh = (int*)alloc((size_t)NCHUNK * NBMAX * 4);  // transient histograms
  const size_t FO_SZ = (size_t)NCHUNK * (NBMAX + 1) * 4;
  int* fo_hs = (int*)alloc(FO_SZ);
  int* fo_hj = (int*)alloc(FO_SZ);
  int* fo_hp = (int*)alloc(FO_SZ);
  int* fo_iu = (int*)alloc(FO_SZ);
  int* fo_ii = (int*)alloc(FO_SZ);
  int2* st_hs = (int2*)alloc((size_t)NH * 8);
  int2* st_hj = (int2*)alloc((size_t)NH * 8);
  int2* st_hp = (int2*)alloc((size_t)NH * 8);
  int2* st_iu = (int2*)alloc((size_t)NI * 8);
  int2* st_ii = (int2*)alloc((size_t)NI * 8);
  size_t needed = (size_t)(p - (char*)d_ws);
  // bucket path: cols must fit 24-bit packed field, buckets must fit NBMAX
  bool use_csr = needed <= ws_size && U < (1 << 24) && I < (1 << 24) &&
                 U <= NBMAX * BSZ && I <= NBMAX * BSZ;

  const int ROWB_U = (U + 3) / 4;  // wave-per-row blocks (fallback helpers)
  const int ROWB_I = (I + 3) / 4;
  const int NB_U = (U + BSZ - 1) >> SB;
  const int NB_I = (I + BSZ - 1) >> SB;
  const int SPMM_BLOCKS = 2048;

  // v = att_mat @ att_agg^T
  hipLaunchKernelGGL(compute_v_kernel, dim3(1), dim3(64), 0, stream, att_mat,
                     att_agg, v);
  // self-gating (4 channels); acc copies only needed on fallback path
  hipLaunchKernelGGL(gating4_kernel, dim3(512), dim3(256), 0, stream, user_emb,
                     gating_w, gating_b, u0, u1, u2, us,
                     use_csr ? (float*)nullptr : acc0,
                     use_csr ? (float*)nullptr : acc1,
                     use_csr ? (float*)nullptr : acc2,
                     use_csr ? (float*)nullptr : accS, U);
  if (!use_csr) {
    hipMemcpyAsync(acc_item, item_emb, ID * sizeof(float),
                   hipMemcpyDeviceToDevice, stream);
    hipMemcpyAsync(it_a, item_emb, ID * sizeof(float), hipMemcpyDeviceToDevice,
                   stream);
  }

  if (use_csr) {
    build_buckets(hs_row, hs_col, hs_val, NH, U, bh, fo_hs, st_hs, stream);
    build_buckets(hj_row, hj_col, hj_val, NH, U, bh, fo_hj, st_hj, stream);
    build_buckets(hp_row, hp_col, hp_val, NH, U, bh, fo_hp, st_hp, stream);
    build_buckets(inter_row, inter_col, inter_val, NI, U, bh, fo_iu, st_iu,
                  stream);
    build_buckets(inter_col, inter_row, inter_val, NI, I, bh, fo_ii, st_ii,
                  stream);
  }

  // bucket path: layer-0 item source is item_emb directly (no copy)
  const float* it_src = item_emb;
  float* it_dst = it_b;
  // fallback path pointers
  float* it_old = it_a;
  float* it_new = it_b;

  for (int layer = 0; layer < 2; ++layer) {
    hipLaunchKernelGGL(attn_mix_kernel, dim3(ROWB_U), dim3(256), 0, stream, u0,
                       u1, u2, us, v, mixed, U);
    if (use_csr) {
      const float* i0 = (layer == 0) ? u0 : nullptr;
      const float* i1 = (layer == 0) ? u1 : nullptr;
      const float* i2 = (layer == 0) ? u2 : nullptr;
      const float* ii = (layer == 0) ? item_emb : nullptr;
      const float* is = (layer == 0) ? us : nullptr;
      hipLaunchKernelGGL(spmm_bucket_l2acc_kernel, dim3(NB_U), dim3(256), 0,
                         stream, fo_hs, st_hs, u0, spare, acc0, i0, U, NB_U);
      { float* t = u0; u0 = spare; spare = t; }
      hipLaunchKernelGGL(spmm_bucket_l2acc_kernel, dim3(NB_U), dim3(256), 0,
                         stream, fo_hj, st_hj, u1, spare, acc1, i1, U, NB_U);
      { float* t = u1; u1 = spare; spare = t; }
      hipLaunchKernelGGL(spmm_bucket_l2acc_kernel, dim3(NB_U), dim3(256), 0,
                         stream, fo_hp, st_hp, u2, spare, acc2, i2, U, NB_U);
      { float* t = u2; u2 = spare; spare = t; }
      hipLaunchKernelGGL(spmm_bucket_l2acc_kernel, dim3(NB_I), dim3(256), 0,
                         stream, fo_ii, st_ii, mixed, it_dst, acc_item, ii, I,
                         NB_I);
      hipLaunchKernelGGL(spmm_bucket_l2acc_kernel, dim3(NB_U), dim3(256), 0,
                         stream, fo_iu, st_iu, it_src, spare, accS, is, U,
                         NB_U);
      { float* t = us; us = spare; spare = t; }
      it_src = it_dst;
      it_dst = it_a;
    } else {
      hipMemsetAsync(spare, 0, UD * sizeof(float), stream);
      hipLaunchKernelGGL(spmm_atomic_kernel, dim3(SPMM_BLOCKS), dim3(256), 0,
                         stream, hs_row, hs_col, hs_val, u0, spare, NH);
      hipLaunchKernelGGL(l2acc_kernel, dim3(ROWB_U), dim3(256), 0, stream,
                         spare, acc0, U);
      { float* t = u0; u0 = spare; spare = t; }
      hipMemsetAsync(spare, 0, UD * sizeof(float), stream);
      hipLaunchKernelGGL(spmm_atomic_kernel, dim3(SPMM_BLOCKS), dim3(256), 0,
                         stream, hj_row, hj_col, hj_val, u1, spare, NH);
      hipLaunchKernelGGL(l2acc_kernel, dim3(ROWB_U), dim3(256), 0, stream,
                         spare, acc1, U);
      { float* t = u1; u1 = spare; spare = t; }
      hipMemsetAsync(spare, 0, UD * sizeof(float), stream);
      hipLaunchKernelGGL(spmm_atomic_kernel, dim3(SPMM_BLOCKS), dim3(256), 0,
                         stream, hp_row, hp_col, hp_val, u2, spare, NH);
      hipLaunchKernelGGL(l2acc_kernel, dim3(ROWB_U), dim3(256), 0, stream,
                         spare, acc2, U);
      { float* t = u2; u2 = spare; spare = t; }
      hipMemsetAsync(it_new, 0, ID * sizeof(float), stream);
      hipLaunchKernelGGL(spmm_atomic_kernel, dim3(SPMM_BLOCKS), dim3(256), 0,
                         stream, inter_col, inter_row, inter_val, mixed, it_new,
                         NI);
      hipLaunchKernelGGL(l2acc_kernel, dim3(ROWB_I), dim3(256), 0, stream,
                         it_new, acc_item, I);
      hipMemsetAsync(spare, 0, UD * sizeof(float), stream);
      hipLaunchKernelGGL(spmm_atomic_kernel, dim3(SPMM_BLOCKS), dim3(256), 0,
                         stream, inter_row, inter_col, inter_val, it_old, spare,
                         NI);
      hipLaunchKernelGGL(l2acc_kernel, dim3(ROWB_U), dim3(256), 0, stream,
                         spare, accS, U);
      { float* t = us; us = spare; spare = t; }
      { float* t = it_old; it_old = it_new; it_new = t; }
    }
  }

  hipLaunchKernelGGL(final_attn_kernel, dim3(ROWB_U), dim3(256), 0, stream,
                     acc0, acc1, acc2, accS, v, final_user, U);
  hipLaunchKernelGGL(sgating3_kernel, dim3(512), dim3(256), 0, stream,
                     final_user, sgating_w, sgating_b, sg0, sg1, sg2, U);
}

// Round 6
// 3215.979 us; speedup vs baseline: 4.3557x; 4.3557x over previous
//
#include <hip/hip_runtime.h>

#define D 64
#define EPS 1e-12f

// bucket = row >> SB  (64 rows per bucket)
#define SB 6
#define BSZ (1 << SB)
#define NBMAX 2048        // max buckets -> supports nrows <= 131072
#define NCHUNK 128        // edge chunks for the partition

__device__ __forceinline__ float wave_sum(float v) {
#pragma unroll
  for (int off = 32; off > 0; off >>= 1) v += __shfl_xor(v, off, 64);
  return v;
}

// v[d] = sum_j att_mat[d, j] * att_agg[j]
__global__ void compute_v_kernel(const float* __restrict__ att_mat,
                                 const float* __restrict__ att_agg,
                                 float* __restrict__ v) {
  int d = threadIdx.x;
  float s = 0.f;
#pragma unroll
  for (int j = 0; j < D; ++j) s += att_mat[d * D + j] * att_agg[j];
  v[d] = s;
}

// u_k = emb * sigmoid(emb @ W_k + b_k) for k=0..3.
// W channel-interleaved in LDS as float4[j][lane]; row-blocked R=4.
__global__ __launch_bounds__(256) void gating4_kernel(
    const float* __restrict__ emb, const float* __restrict__ W,
    const float* __restrict__ B, float* __restrict__ u0, float* __restrict__ u1,
    float* __restrict__ u2, float* __restrict__ u3, float* __restrict__ a0,
    float* __restrict__ a1, float* __restrict__ a2, float* __restrict__ a3,
    int nrows) {
  __shared__ float4 sW4[D * D];  // 64 KiB
  for (int i = threadIdx.x; i < D * D; i += blockDim.x)
    sW4[i] = make_float4(W[i], W[D * D + i], W[2 * D * D + i],
                         W[3 * D * D + i]);
  __syncthreads();
  int lane = threadIdx.x & 63;
  int wid = (blockIdx.x * blockDim.x + threadIdx.x) >> 6;
  int nw = (gridDim.x * blockDim.x) >> 6;
  float b0 = B[0 * D + lane], b1 = B[1 * D + lane];
  float b2 = B[2 * D + lane], b3 = B[3 * D + lane];
  for (int r0 = wid * 4; r0 < nrows; r0 += nw * 4) {
    float e[4];
    float y[4][4];
#pragma unroll
    for (int i = 0; i < 4; ++i) {
      int r = r0 + i < nrows ? r0 + i : r0;
      e[i] = emb[(size_t)r * D + lane];
      y[i][0] = b0; y[i][1] = b1; y[i][2] = b2; y[i][3] = b3;
    }
#pragma unroll 16
    for (int j = 0; j < D; ++j) {
      float4 w = sW4[j * D + lane];
#pragma unroll
      for (int i = 0; i < 4; ++i) {
        float ej = __shfl(e[i], j, 64);
        y[i][0] += ej * w.x;
        y[i][1] += ej * w.y;
        y[i][2] += ej * w.z;
        y[i][3] += ej * w.w;
      }
    }
#pragma unroll
    for (int i = 0; i < 4; ++i) {
      int r = r0 + i;
      if (r < nrows) {
        size_t idx = (size_t)r * D + lane;
        float o0 = e[i] / (1.f + __expf(-y[i][0]));
        float o1 = e[i] / (1.f + __expf(-y[i][1]));
        float o2 = e[i] / (1.f + __expf(-y[i][2]));
        float o3 = e[i] / (1.f + __expf(-y[i][3]));
        u0[idx] = o0; u1[idx] = o1; u2[idx] = o2; u3[idx] = o3;
        if (a0) { a0[idx] = o0; a1[idx] = o1; a2[idx] = o2; a3[idx] = o3; }
      }
    }
  }
}

// sg_k = x * sigmoid(x @ W_k + b_k) for k=0..2 (same structure as gating4)
__global__ __launch_bounds__(256) void sgating3_kernel(
    const float* __restrict__ x, const float* __restrict__ W,
    const float* __restrict__ B, float* __restrict__ o0f,
    float* __restrict__ o1f, float* __restrict__ o2f, int nrows) {
  __shared__ float4 sW4[D * D];
  for (int i = threadIdx.x; i < D * D; i += blockDim.x)
    sW4[i] = make_float4(W[i], W[D * D + i], W[2 * D * D + i], 0.f);
  __syncthreads();
  int lane = threadIdx.x & 63;
  int wid = (blockIdx.x * blockDim.x + threadIdx.x) >> 6;
  int nw = (gridDim.x * blockDim.x) >> 6;
  float b0 = B[0 * D + lane], b1 = B[1 * D + lane], b2 = B[2 * D + lane];
  for (int r0 = wid * 4; r0 < nrows; r0 += nw * 4) {
    float e[4];
    float y[4][3];
#pragma unroll
    for (int i = 0; i < 4; ++i) {
      int r = r0 + i < nrows ? r0 + i : r0;
      e[i] = x[(size_t)r * D + lane];
      y[i][0] = b0; y[i][1] = b1; y[i][2] = b2;
    }
#pragma unroll 16
    for (int j = 0; j < D; ++j) {
      float4 w = sW4[j * D + lane];
#pragma unroll
      for (int i = 0; i < 4; ++i) {
        float ej = __shfl(e[i], j, 64);
        y[i][0] += ej * w.x;
        y[i][1] += ej * w.y;
        y[i][2] += ej * w.z;
      }
    }
#pragma unroll
    for (int i = 0; i < 4; ++i) {
      int r = r0 + i;
      if (r < nrows) {
        size_t idx = (size_t)r * D + lane;
        o0f[idx] = e[i] / (1.f + __expf(-y[i][0]));
        o1f[idx] = e[i] / (1.f + __expf(-y[i][1]));
        o2f[idx] = e[i] / (1.f + __expf(-y[i][2]));
      }
    }
  }
}

// mixed = (softmax-weighted(u0,u1,u2) + us) * 0.5
__global__ __launch_bounds__(256) void attn_mix_kernel(
    const float* __restrict__ u0, const float* __restrict__ u1,
    const float* __restrict__ u2, const float* __restrict__ us,
    const float* __restrict__ v, float* __restrict__ mixed, int nrows) {
  int lane = threadIdx.x & 63;
  int wid = (blockIdx.x * blockDim.x + threadIdx.x) >> 6;
  if (wid >= nrows) return;
  int idx = wid * D + lane;
  float e0 = u0[idx], e1 = u1[idx], e2 = u2[idx], eu = us[idx];
  float vd = v[lane];
  float w0 = wave_sum(e0 * vd);
  float w1 = wave_sum(e1 * vd);
  float w2 = wave_sum(e2 * vd);
  float m = fmaxf(w0, fmaxf(w1, w2));
  float s0 = __expf(w0 - m), s1 = __expf(w1 - m), s2 = __expf(w2 - m);
  float inv = 1.f / (s0 + s1 + s2);
  mixed[idx] = ((s0 * e0 + s1 * e1 + s2 * e2) * inv + eu) * 0.5f;
}

// out = softmax-weighted(a0,a1,a2) + 0.5*as  (as may alias out; per-element safe)
__global__ __launch_bounds__(256) void final_attn_kernel(
    const float* __restrict__ a0, const float* __restrict__ a1,
    const float* __restrict__ a2, const float* __restrict__ as,
    const float* __restrict__ v, float* __restrict__ out, int nrows) {
  int lane = threadIdx.x & 63;
  int wid = (blockIdx.x * blockDim.x + threadIdx.x) >> 6;
  if (wid >= nrows) return;
  int idx = wid * D + lane;
  float e0 = a0[idx], e1 = a1[idx], e2 = a2[idx], eu = as[idx];
  float vd = v[lane];
  float w0 = wave_sum(e0 * vd);
  float w1 = wave_sum(e1 * vd);
  float w2 = wave_sum(e2 * vd);
  float m = fmaxf(w0, fmaxf(w1, w2));
  float s0 = __expf(w0 - m), s1 = __expf(w1 - m), s2 = __expf(w2 - m);
  float inv = 1.f / (s0 + s1 + s2);
  out[idx] = (s0 * e0 + s1 * e1 + s2 * e2) * inv + 0.5f * eu;
}

// acc += x / max(||x_row||, eps)   (fallback path only)
__global__ __launch_bounds__(256) void l2acc_kernel(const float* __restrict__ x,
                                                    float* __restrict__ acc,
                                                    int nrows) {
  int lane = threadIdx.x & 63;
  int wid = (blockIdx.x * blockDim.x + threadIdx.x) >> 6;
  if (wid >= nrows) return;
  int idx = wid * D + lane;
  float xv = x[idx];
  float ss = wave_sum(xv * xv);
  float nrm = fmaxf(sqrtf(ss), EPS);
  acc[idx] += xv / nrm;
}

// out[row[e], :] += val[e] * x[col[e], :]  (fallback atomic scatter)
__global__ __launch_bounds__(256) void spmm_atomic_kernel(
    const int* __restrict__ row, const int* __restrict__ col,
    const float* __restrict__ val, const float* __restrict__ x,
    float* __restrict__ out, int nnz) {
  int lane = threadIdx.x & 63;
  int wid = (blockIdx.x * blockDim.x + threadIdx.x) >> 6;
  int nw = (gridDim.x * blockDim.x) >> 6;
  for (int base = wid * 64; base < nnz; base += nw * 64) {
    int e = base + lane;
    int r = 0, c = 0;
    float v = 0.f;
    if (e < nnz) { r = row[e]; c = col[e]; v = val[e]; }
    int cnt = nnz - base; if (cnt > 64) cnt = 64;
    for (int i = 0; i < cnt; ++i) {
      int ri = __shfl(r, i, 64);
      int ci = __shfl(c, i, 64);
      float vi = __shfl(v, i, 64);
      float xv = x[ci * D + lane];
      atomicAdd(&out[ri * D + lane], vi * xv);
    }
  }
}

// ---------------- CSR build ----------------

__global__ __launch_bounds__(256) void hist_kernel(const int* __restrict__ row,
                                                   int* __restrict__ counts,
                                                   int nnz) {
  int i = blockIdx.x * blockDim.x + threadIdx.x;
  int n = gridDim.x * blockDim.x;
  for (; i < nnz; i += n) atomicAdd(&counts[row[i]], 1);
}

// per-block exclusive scan of 2048 ints; block totals -> partials
__global__ __launch_bounds__(256) void scan1_kernel(const int* __restrict__ in,
                                                    int* __restrict__ out,
                                                    int* __restrict__ partials,
                                                    int n) {
  __shared__ int lds[256];
  int t = threadIdx.x;
  int base = blockIdx.x * 2048 + t * 8;
  int v[8];
  int s = 0;
#pragma unroll
  for (int k = 0; k < 8; ++k) {
    int i = base + k;
    v[k] = (i < n) ? in[i] : 0;
    s += v[k];
  }
  lds[t] = s;
  __syncthreads();
  for (int ofs = 1; ofs < 256; ofs <<= 1) {
    int add = 0;
    if (t >= ofs) add = lds[t - ofs];
    __syncthreads();
    if (t >= ofs) lds[t] += add;
    __syncthreads();
  }
  int excl = lds[t] - s;
  if (t == 255) partials[blockIdx.x] = lds[255];
  int run = excl;
#pragma unroll
  for (int k = 0; k < 8; ++k) {
    int i = base + k;
    if (i < n) out[i] = run;
    run += v[k];
  }
}

// exclusive scan of P (<=256) partials, in place
__global__ __launch_bounds__(256) void scan2_kernel(int* __restrict__ partials,
                                                    int P) {
  __shared__ int lds[256];
  int t = threadIdx.x;
  int s = (t < P) ? partials[t] : 0;
  lds[t] = s;
  __syncthreads();
  for (int ofs = 1; ofs < 256; ofs <<= 1) {
    int add = 0;
    if (t >= ofs) add = lds[t - ofs];
    __syncthreads();
    if (t >= ofs) lds[t] += add;
    __syncthreads();
  }
  if (t < P) partials[t] = lds[t] - s;
}

__global__ __launch_bounds__(256) void scan3_kernel(
    int* __restrict__ out, const int* __restrict__ partials, int n) {
  int i = blockIdx.x * blockDim.x + threadIdx.x;
  int nt = gridDim.x * blockDim.x;
  for (; i < n; i += nt) out[i] += partials[i >> 11];
}

// ---- chunk-major bucket partition (all writes XCD-local) ----
// Pass 1: per-chunk bucket histogram -> bh[k*nb + b].
__global__ __launch_bounds__(256) void bhist_kernel(
    const int* __restrict__ row, int* __restrict__ bh, int nnz, int nb,
    int chunk) {
  __shared__ int hist[NBMAX];
  for (int i = threadIdx.x; i < nb; i += blockDim.x) hist[i] = 0;
  __syncthreads();
  int base = blockIdx.x * chunk;
  int lim = base + chunk;
  if (lim > nnz) lim = nnz;
  for (int e = base + threadIdx.x; e < lim; e += blockDim.x)
    atomicAdd(&hist[row[e] >> SB], 1);
  __syncthreads();
  int* o = bh + (size_t)blockIdx.x * nb;
  for (int i = threadIdx.x; i < nb; i += blockDim.x) o[i] = hist[i];
}

// Pass 2: per-chunk exclusive scan of its nb counts ->
// fo[k*(nb+1)+b] = k*chunk + excl_prefix ; fo[k*(nb+1)+nb] = chunk end.
__global__ __launch_bounds__(256) void chunkscan_kernel(
    const int* __restrict__ bh, int* __restrict__ fo, int nnz, int nb,
    int chunk) {
  __shared__ int lds[256];
  int k = blockIdx.x;
  int base = k * chunk;
  int t = threadIdx.x;
  const int* in = bh + (size_t)k * nb;
  int v[8];
  int s = 0;
#pragma unroll
  for (int q = 0; q < 8; ++q) {
    int b = t * 8 + q;
    v[q] = (b < nb) ? in[b] : 0;
    s += v[q];
  }
  lds[t] = s;
  __syncthreads();
  for (int ofs = 1; ofs < 256; ofs <<= 1) {
    int add = 0;
    if (t >= ofs) add = lds[t - ofs];
    __syncthreads();
    if (t >= ofs) lds[t] += add;
    __syncthreads();
  }
  int run = base + lds[t] - s;
  int* o = fo + (size_t)k * (nb + 1);
#pragma unroll
  for (int q = 0; q < 8; ++q) {
    int b = t * 8 + q;
    if (b < nb) o[b] = run;
    run += v[q];
  }
  if (t == 255) o[nb] = run;  // = base + edges-in-chunk
}

// Pass 3: scatter edges bucket-grouped WITHIN the block's own contiguous
// region [k*chunk, ...). Every staging line is written by exactly one
// block (one XCD) over a ~200 KB L2-resident window -> full-line
// writebacks, compulsory-only HBM writes. (The old bucket-major layout
// shared boundary lines across XCDs: 86 MB writes, 146 us.) lrow packed
// into col's high 8 bits.
__global__ __launch_bounds__(256) void bscatter2_kernel(
    const int* __restrict__ row, const int* __restrict__ col,
    const float* __restrict__ val, const int* __restrict__ fo,
    int2* __restrict__ staging, int nnz, int nb, int chunk) {
  __shared__ int cur[NBMAX];
  const int* o = fo + (size_t)blockIdx.x * (nb + 1);
  for (int i = threadIdx.x; i < nb; i += blockDim.x) cur[i] = o[i];
  __syncthreads();
  int base = blockIdx.x * chunk;
  int lim = base + chunk;
  if (lim > nnz) lim = nnz;
  for (int e = base + threadIdx.x; e < lim; e += blockDim.x) {
    int r = row[e];
    int b = r >> SB;
    int idx = atomicAdd(&cur[b], 1);
    staging[idx] =
        make_int2(((r & (BSZ - 1)) << 24) | col[e], __float_as_int(val[e]));
  }
}

// Pass 4: one block per bucket; finalize exact CSR order. Fragment
// extents are preloaded into LDS in one shot (no serial fo-load chain —
// that chain was round-5's 1360us mistake). Row cursors in LDS from
// row_ptr; all writes land in this bucket's ~16 KB output region ->
// L2-absorbed full-line writebacks.
__global__ __launch_bounds__(256) void bucket_gather_kernel(
    const int* __restrict__ row_ptr, const int* __restrict__ fo,
    const int2* __restrict__ staging, int2* __restrict__ edges_out, int nrows,
    int nb) {
  __shared__ int lfill[BSZ];
  __shared__ int2 sfrag[NCHUNK];
  int b = blockIdx.x;
  int t = threadIdx.x;
  if (t < BSZ) {
    int r = (b << SB) + t;
    lfill[t] = row_ptr[r < nrows ? r : nrows];
  }
  if (t < NCHUNK) {
    const int* o = fo + (size_t)t * (nb + 1) + b;
    sfrag[t] = make_int2(o[0], o[1]);
  }
  __syncthreads();
  int lane = t & 63;
  int w = t >> 6;
  for (int k = w; k < NCHUNK; k += 4) {
    int2 f = sfrag[k];
    for (int e = f.x + lane; e < f.y; e += 64) {
      int2 ev = staging[e];
      int lrow = ((unsigned)ev.x) >> 24;
      int idx = atomicAdd(&lfill[lrow], 1);
      edges_out[idx] = make_int2(ev.x & 0xFFFFFF, ev.y);
    }
  }
}

// ---------------- fused CSR SpMM + l2norm-accumulate ----------------
// out[r,:] = sum_e val[e]*x[col[e],:]
// acc[r,:] = (init ? init[r,:] : acc[r,:]) + out[r,:]/max(||out[r,:]||,eps)
// One wave per row; 4-deep gather pipelining.
__global__ __launch_bounds__(256) void spmm_csr_l2acc_kernel(
    const int* __restrict__ row_ptr, const int2* __restrict__ edges,
    const float* __restrict__ x, float* __restrict__ out,
    float* __restrict__ acc, const float* __restrict__ init, int nrows) {
  int lane = threadIdx.x & 63;
  int r = (blockIdx.x * blockDim.x + threadIdx.x) >> 6;
  if (r >= nrows) return;
  int start = row_ptr[r], end = row_ptr[r + 1];
  float sum = 0.f;
  for (int j = start; j < end; j += 64) {
    int e = j + lane;
    int c = 0;
    float v = 0.f;
    if (e < end) {
      int2 ev = edges[e];
      c = ev.x;
      v = __int_as_float(ev.y);
    }
    int cnt = end - j;
    if (cnt > 64) cnt = 64;
    int i = 0;
    for (; i + 4 <= cnt; i += 4) {
      int c0 = __shfl(c, i, 64);
      int c1 = __shfl(c, i + 1, 64);
      int c2 = __shfl(c, i + 2, 64);
      int c3 = __shfl(c, i + 3, 64);
      float v0 = __shfl(v, i, 64);
      float v1 = __shfl(v, i + 1, 64);
      float v2 = __shfl(v, i + 2, 64);
      float v3 = __shfl(v, i + 3, 64);
      float x0 = x[c0 * D + lane];
      float x1 = x[c1 * D + lane];
      float x2 = x[c2 * D + lane];
      float x3 = x[c3 * D + lane];
      sum += v0 * x0;
      sum += v1 * x1;
      sum += v2 * x2;
      sum += v3 * x3;
    }
    for (; i < cnt; ++i) {
      int ci = __shfl(c, i, 64);
      float vi = __shfl(v, i, 64);
      sum += vi * x[ci * D + lane];
    }
  }
  int idx = r * D + lane;
  out[idx] = sum;
  float ss = wave_sum(sum * sum);
  float nrm = fmaxf(sqrtf(ss), EPS);
  float base = init ? init[idx] : acc[idx];
  acc[idx] = base + sum / nrm;
}

// ---------------- host ----------------

static void build_csr(const int* row, const int* col, const float* val, int nnz,
                      int nrows, int* counts, int* row_ptr, int* partials,
                      int* bh, int* fo, int2* staging, int2* edges_out,
                      hipStream_t stream) {
  int n1 = nrows + 1;
  hipMemsetAsync(counts, 0, n1 * sizeof(int), stream);
  hipLaunchKernelGGL(hist_kernel, dim3(1024), dim3(256), 0, stream, row, counts,
                     nnz);
  int nblk = (n1 + 2047) / 2048;
  hipLaunchKernelGGL(scan1_kernel, dim3(nblk), dim3(256), 0, stream, counts,
                     row_ptr, partials, n1);
  hipLaunchKernelGGL(scan2_kernel, dim3(1), dim3(256), 0, stream, partials,
                     nblk);
  hipLaunchKernelGGL(scan3_kernel, dim3(64), dim3(256), 0, stream, row_ptr,
                     partials, n1);
  int nb = (nrows + BSZ - 1) >> SB;
  int chunk = (nnz + NCHUNK - 1) / NCHUNK;
  hipLaunchKernelGGL(bhist_kernel, dim3(NCHUNK), dim3(256), 0, stream, row, bh,
                     nnz, nb, chunk);
  hipLaunchKernelGGL(chunkscan_kernel, dim3(NCHUNK), dim3(256), 0, stream, bh,
                     fo, nnz, nb, chunk);
  hipLaunchKernelGGL(bscatter2_kernel, dim3(NCHUNK), dim3(256), 0, stream, row,
                     col, val, fo, staging, nnz, nb, chunk);
  hipLaunchKernelGGL(bucket_gather_kernel, dim3(nb), dim3(256), 0, stream,
                     row_ptr, fo, staging, edges_out, nrows, nb);
}

extern "C" void kernel_launch(void* const* d_in, const int* in_sizes, int n_in,
                              void* d_out, int out_size, void* d_ws,
                              size_t ws_size, hipStream_t stream) {
  const float* user_emb = (const float*)d_in[0];
  const float* item_emb = (const float*)d_in[1];
  const float* gating_w = (const float*)d_in[2];
  const float* gating_b = (const float*)d_in[3];
  const float* sgating_w = (const float*)d_in[4];
  const float* sgating_b = (const float*)d_in[5];
  const float* att_mat = (const float*)d_in[6];
  const float* att_agg = (const float*)d_in[7];
  const int* hs_row = (const int*)d_in[8];
  const int* hs_col = (const int*)d_in[9];
  const float* hs_val = (const float*)d_in[10];
  const int* hj_row = (const int*)d_in[11];
  const int* hj_col = (const int*)d_in[12];
  const float* hj_val = (const float*)d_in[13];
  const int* hp_row = (const int*)d_in[14];
  const int* hp_col = (const int*)d_in[15];
  const float* hp_val = (const float*)d_in[16];
  const int* inter_row = (const int*)d_in[17];
  const int* inter_col = (const int*)d_in[18];
  const float* inter_val = (const float*)d_in[19];

  const int U = in_sizes[0] / D;  // 100000
  const int I = in_sizes[1] / D;  // 50000
  const int NH = in_sizes[8];     // 3200000
  const int NI = in_sizes[17];    // 3000000
  const size_t UD = (size_t)U * D;
  const size_t ID = (size_t)I * D;

  float* out = (float*)d_out;
  float* final_user = out;  // also acc_simple storage
  float* acc_item = out + UD;
  float* sg0 = out + UD + ID;  // also acc_c0
  float* sg1 = sg0 + UD;       // also acc_c1
  float* sg2 = sg1 + UD;       // also acc_c2
  float* acc0 = sg0, *acc1 = sg1, *acc2 = sg2, *accS = final_user;

  // ---- workspace bump allocator ----
  char* p = (char*)d_ws;
  auto alloc = [&](size_t bytes) -> void* {
    void* r = (void*)p;
    p += (bytes + 255) & ~(size_t)255;
    return r;
  };
  float* u0 = (float*)alloc(UD * 4);
  float* u1 = (float*)alloc(UD * 4);
  float* u2 = (float*)alloc(UD * 4);
  float* us = (float*)alloc(UD * 4);
  float* mixed = (float*)alloc(UD * 4);
  float* spare = (float*)alloc(UD * 4);
  float* it_a = (float*)alloc(ID * 4);
  float* it_b = (float*)alloc(ID * 4);
  float* v = (float*)alloc(256 * 4);
  int* partials = (int*)alloc(256 * 4);
  // CSR structures
  int* cnt_u = (int*)alloc((U + 2) * 4);  // shared counts buffer (user)
  int* cnt_i = (int*)alloc((I + 2) * 4);  // (item)
  int* bh = (int*)alloc((size_t)NCHUNK * NBMAX * 4);       // transient
  int* fo = (int*)alloc((size_t)NCHUNK * (NBMAX + 1) * 4); // transient
  int* rp_hs = (int*)alloc((U + 2) * 4);
  int* rp_hj = (int*)alloc((U + 2) * 4);
  int* rp_hp = (int*)alloc((U + 2) * 4);
  int* rp_iu = (int*)alloc((U + 2) * 4);
  int* rp_ii = (int*)alloc((I + 2) * 4);
  // staging is only live inside build_csr (all before the layer loop);
  // spare is first written after all builds complete (same in-order
  // stream) -> alias them when it fits.
  size_t NMAX = (size_t)(NH > NI ? NH : NI);
  int2* staging;
  if (NMAX * 8 <= UD * 4) staging = (int2*)spare;
  else staging = (int2*)alloc(NMAX * 8);
  int2* ed_hs = (int2*)alloc((size_t)NH * 8);
  int2* ed_hj = (int2*)alloc((size_t)NH * 8);
  int2* ed_hp = (int2*)alloc((size_t)NH * 8);
  int2* ed_iu = (int2*)alloc((size_t)NI * 8);
  int2* ed_ii = (int2*)alloc((size_t)NI * 8);
  size_t needed = (size_t)(p - (char*)d_ws);
  // CSR path: cols must fit 24-bit packed field, buckets must fit NBMAX
  bool use_csr = needed <= ws_size && U < (1 << 24) && I < (1 << 24) &&
                 U <= NBMAX * BSZ && I <= NBMAX * BSZ;

  const int ROWB_U = (U + 3) / 4;  // wave-per-row blocks (256 thr = 4 waves)
  const int ROWB_I = (I + 3) / 4;
  const int SPMM_BLOCKS = 2048;

  // v = att_mat @ att_agg^T
  hipLaunchKernelGGL(compute_v_kernel, dim3(1), dim3(64), 0, stream, att_mat,
                     att_agg, v);
  // self-gating (4 channels); acc copies only needed on fallback path
  hipLaunchKernelGGL(gating4_kernel, dim3(512), dim3(256), 0, stream, user_emb,
                     gating_w, gating_b, u0, u1, u2, us,
                     use_csr ? (float*)nullptr : acc0,
                     use_csr ? (float*)nullptr : acc1,
                     use_csr ? (float*)nullptr : acc2,
                     use_csr ? (float*)nullptr : accS, U);
  if (!use_csr) {
    hipMemcpyAsync(acc_item, item_emb, ID * sizeof(float),
                   hipMemcpyDeviceToDevice, stream);
    hipMemcpyAsync(it_a, item_emb, ID * sizeof(float), hipMemcpyDeviceToDevice,
                   stream);
  }

  if (use_csr) {
    build_csr(hs_row, hs_col, hs_val, NH, U, cnt_u, rp_hs, partials, bh, fo,
              staging, ed_hs, stream);
    build_csr(hj_row, hj_col, hj_val, NH, U, cnt_u, rp_hj, partials, bh, fo,
              staging, ed_hj, stream);
    build_csr(hp_row, hp_col, hp_val, NH, U, cnt_u, rp_hp, partials, bh, fo,
              staging, ed_hp, stream);
    build_csr(inter_row, inter_col, inter_val, NI, U, cnt_u, rp_iu, partials,
              bh, fo, staging, ed_iu, stream);
    build_csr(inter_col, inter_row, inter_val, NI, I, cnt_i, rp_ii, partials,
              bh, fo, staging, ed_ii, stream);
  }

  // CSR path: layer-0 item source is item_emb directly (no it_a copy)
  const float* it_src = item_emb;
  float* it_dst = it_b;
  // fallback path pointers
  float* it_old = it_a;
  float* it_new = it_b;

  for (int layer = 0; layer < 2; ++layer) {
    hipLaunchKernelGGL(attn_mix_kernel, dim3(ROWB_U), dim3(256), 0, stream, u0,
                       u1, u2, us, v, mixed, U);
    if (use_csr) {
      const float* i0 = (layer == 0) ? u0 : nullptr;
      const float* i1 = (layer == 0) ? u1 : nullptr;
      const float* i2 = (layer == 0) ? u2 : nullptr;
      const float* ii = (layer == 0) ? item_emb : nullptr;
      const float* is = (layer == 0) ? us : nullptr;
      hipLaunchKernelGGL(spmm_csr_l2acc_kernel, dim3(ROWB_U), dim3(256), 0,
                         stream, rp_hs, ed_hs, u0, spare, acc0, i0, U);
      { float* t = u0; u0 = spare; spare = t; }
      hipLaunchKernelGGL(spmm_csr_l2acc_kernel, dim3(ROWB_U), dim3(256), 0,
                         stream, rp_hj, ed_hj, u1, spare, acc1, i1, U);
      { float* t = u1; u1 = spare; spare = t; }
      hipLaunchKernelGGL(spmm_csr_l2acc_kernel, dim3(ROWB_U), dim3(256), 0,
                         stream, rp_hp, ed_hp, u2, spare, acc2, i2, U);
      { float* t = u2; u2 = spare; spare = t; }
      hipLaunchKernelGGL(spmm_csr_l2acc_kernel, dim3(ROWB_I), dim3(256), 0,
                         stream, rp_ii, ed_ii, mixed, it_dst, acc_item, ii, I);
      hipLaunchKernelGGL(spmm_csr_l2acc_kernel, dim3(ROWB_U), dim3(256), 0,
                         stream, rp_iu, ed_iu, it_src, spare, accS, is, U);
      { float* t = us; us = spare; spare = t; }
      it_src = it_dst;
      it_dst = it_a;
    } else {
      hipMemsetAsync(spare, 0, UD * sizeof(float), stream);
      hipLaunchKernelGGL(spmm_atomic_kernel, dim3(SPMM_BLOCKS), dim3(256), 0,
                         stream, hs_row, hs_col, hs_val, u0, spare, NH);
      hipLaunchKernelGGL(l2acc_kernel, dim3(ROWB_U), dim3(256), 0, stream,
                         spare, acc0, U);
      { float* t = u0; u0 = spare; spare = t; }
      hipMemsetAsync(spare, 0, UD * sizeof(float), stream);
      hipLaunchKernelGGL(spmm_atomic_kernel, dim3(SPMM_BLOCKS), dim3(256), 0,
                         stream, hj_row, hj_col, hj_val, u1, spare, NH);
      hipLaunchKernelGGL(l2acc_kernel, dim3(ROWB_U), dim3(256), 0, stream,
                         spare, acc1, U);
      { float* t = u1; u1 = spare; spare = t; }
      hipMemsetAsync(spare, 0, UD * sizeof(float), stream);
      hipLaunchKernelGGL(spmm_atomic_kernel, dim3(SPMM_BLOCKS), dim3(256), 0,
                         stream, hp_row, hp_col, hp_val, u2, spare, NH);
      hipLaunchKernelGGL(l2acc_kernel, dim3(ROWB_U), dim3(256), 0, stream,
                         spare, acc2, U);
      { float* t = u2; u2 = spare; spare = t; }
      hipMemsetAsync(it_new, 0, ID * sizeof(float), stream);
      hipLaunchKernelGGL(spmm_atomic_kernel, dim3(SPMM_BLOCKS), dim3(256), 0,
                         stream, inter_col, inter_row, inter_val, mixed, it_new,
                         NI);
      hipLaunchKernelGGL(l2acc_kernel, dim3(ROWB_I), dim3(256), 0, stream,
                         it_new, acc_item, I);
      hipMemsetAsync(spare, 0, UD * sizeof(float), stream);
      hipLaunchKernelGGL(spmm_atomic_kernel, dim3(SPMM_BLOCKS), dim3(256), 0,
                         stream, inter_row, inter_col, inter_val, it_old, spare,
                         NI);
      hipLaunchKernelGGL(l2acc_kernel, dim3(ROWB_U), dim3(256), 0, stream,
                         spare, accS, U);
      { float* t = us; us = spare; spare = t; }
      { float* t = it_old; it_old = it_new; it_new = t; }
    }
  }

  hipLaunchKernelGGL(final_attn_kernel, dim3(ROWB_U), dim3(256), 0, stream,
                     acc0, acc1, acc2, accS, v, final_user, U);
  hipLaunchKernelGGL(sgating3_kernel, dim3(512), dim3(256), 0, stream,
                     final_user, sgating_w, sgating_b, sg0, sg1, sg2, U);
}

// Round 7
// 2796.081 us; speedup vs baseline: 5.0099x; 1.1502x over previous
//
#include <hip/hip_runtime.h>

#define D 64
#define EPS 1e-12f

// bucket = row >> SB  (64 rows per bucket)
#define SB 6
#define BSZ (1 << SB)
#define NBMAX 2048        // max buckets -> supports nrows <= 131072
#define NCHUNK 1024       // edge chunks; chunk size must be <= CMAX
#define CMAX 4096         // max edges per chunk (LDS sort buffer)

__device__ __forceinline__ float wave_sum(float v) {
#pragma unroll
  for (int off = 32; off > 0; off >>= 1) v += __shfl_xor(v, off, 64);
  return v;
}

// v[d] = sum_j att_mat[d, j] * att_agg[j]
__global__ void compute_v_kernel(const float* __restrict__ att_mat,
                                 const float* __restrict__ att_agg,
                                 float* __restrict__ v) {
  int d = threadIdx.x;
  float s = 0.f;
#pragma unroll
  for (int j = 0; j < D; ++j) s += att_mat[d * D + j] * att_agg[j];
  v[d] = s;
}

// u_k = emb * sigmoid(emb @ W_k + b_k) for k=0..3.
// W channel-interleaved in LDS as float4[j][lane]; row-blocked R=4.
__global__ __launch_bounds__(256) void gating4_kernel(
    const float* __restrict__ emb, const float* __restrict__ W,
    const float* __restrict__ B, float* __restrict__ u0, float* __restrict__ u1,
    float* __restrict__ u2, float* __restrict__ u3, float* __restrict__ a0,
    float* __restrict__ a1, float* __restrict__ a2, float* __restrict__ a3,
    int nrows) {
  __shared__ float4 sW4[D * D];  // 64 KiB
  for (int i = threadIdx.x; i < D * D; i += blockDim.x)
    sW4[i] = make_float4(W[i], W[D * D + i], W[2 * D * D + i],
                         W[3 * D * D + i]);
  __syncthreads();
  int lane = threadIdx.x & 63;
  int wid = (blockIdx.x * blockDim.x + threadIdx.x) >> 6;
  int nw = (gridDim.x * blockDim.x) >> 6;
  float b0 = B[0 * D + lane], b1 = B[1 * D + lane];
  float b2 = B[2 * D + lane], b3 = B[3 * D + lane];
  for (int r0 = wid * 4; r0 < nrows; r0 += nw * 4) {
    float e[4];
    float y[4][4];
#pragma unroll
    for (int i = 0; i < 4; ++i) {
      int r = r0 + i < nrows ? r0 + i : r0;
      e[i] = emb[(size_t)r * D + lane];
      y[i][0] = b0; y[i][1] = b1; y[i][2] = b2; y[i][3] = b3;
    }
#pragma unroll 16
    for (int j = 0; j < D; ++j) {
      float4 w = sW4[j * D + lane];
#pragma unroll
      for (int i = 0; i < 4; ++i) {
        float ej = __shfl(e[i], j, 64);
        y[i][0] += ej * w.x;
        y[i][1] += ej * w.y;
        y[i][2] += ej * w.z;
        y[i][3] += ej * w.w;
      }
    }
#pragma unroll
    for (int i = 0; i < 4; ++i) {
      int r = r0 + i;
      if (r < nrows) {
        size_t idx = (size_t)r * D + lane;
        float o0 = e[i] / (1.f + __expf(-y[i][0]));
        float o1 = e[i] / (1.f + __expf(-y[i][1]));
        float o2 = e[i] / (1.f + __expf(-y[i][2]));
        float o3 = e[i] / (1.f + __expf(-y[i][3]));
        u0[idx] = o0; u1[idx] = o1; u2[idx] = o2; u3[idx] = o3;
        if (a0) { a0[idx] = o0; a1[idx] = o1; a2[idx] = o2; a3[idx] = o3; }
      }
    }
  }
}

// sg_k = x * sigmoid(x @ W_k + b_k) for k=0..2 (same structure as gating4)
__global__ __launch_bounds__(256) void sgating3_kernel(
    const float* __restrict__ x, const float* __restrict__ W,
    const float* __restrict__ B, float* __restrict__ o0f,
    float* __restrict__ o1f, float* __restrict__ o2f, int nrows) {
  __shared__ float4 sW4[D * D];
  for (int i = threadIdx.x; i < D * D; i += blockDim.x)
    sW4[i] = make_float4(W[i], W[D * D + i], W[2 * D * D + i], 0.f);
  __syncthreads();
  int lane = threadIdx.x & 63;
  int wid = (blockIdx.x * blockDim.x + threadIdx.x) >> 6;
  int nw = (gridDim.x * blockDim.x) >> 6;
  float b0 = B[0 * D + lane], b1 = B[1 * D + lane], b2 = B[2 * D + lane];
  for (int r0 = wid * 4; r0 < nrows; r0 += nw * 4) {
    float e[4];
    float y[4][3];
#pragma unroll
    for (int i = 0; i < 4; ++i) {
      int r = r0 + i < nrows ? r0 + i : r0;
      e[i] = x[(size_t)r * D + lane];
      y[i][0] = b0; y[i][1] = b1; y[i][2] = b2;
    }
#pragma unroll 16
    for (int j = 0; j < D; ++j) {
      float4 w = sW4[j * D + lane];
#pragma unroll
      for (int i = 0; i < 4; ++i) {
        float ej = __shfl(e[i], j, 64);
        y[i][0] += ej * w.x;
        y[i][1] += ej * w.y;
        y[i][2] += ej * w.z;
      }
    }
#pragma unroll
    for (int i = 0; i < 4; ++i) {
      int r = r0 + i;
      if (r < nrows) {
        size_t idx = (size_t)r * D + lane;
        o0f[idx] = e[i] / (1.f + __expf(-y[i][0]));
        o1f[idx] = e[i] / (1.f + __expf(-y[i][1]));
        o2f[idx] = e[i] / (1.f + __expf(-y[i][2]));
      }
    }
  }
}

// mixed = (softmax-weighted(u0,u1,u2) + us) * 0.5
__global__ __launch_bounds__(256) void attn_mix_kernel(
    const float* __restrict__ u0, const float* __restrict__ u1,
    const float* __restrict__ u2, const float* __restrict__ us,
    const float* __restrict__ v, float* __restrict__ mixed, int nrows) {
  int lane = threadIdx.x & 63;
  int wid = (blockIdx.x * blockDim.x + threadIdx.x) >> 6;
  if (wid >= nrows) return;
  int idx = wid * D + lane;
  float e0 = u0[idx], e1 = u1[idx], e2 = u2[idx], eu = us[idx];
  float vd = v[lane];
  float w0 = wave_sum(e0 * vd);
  float w1 = wave_sum(e1 * vd);
  float w2 = wave_sum(e2 * vd);
  float m = fmaxf(w0, fmaxf(w1, w2));
  float s0 = __expf(w0 - m), s1 = __expf(w1 - m), s2 = __expf(w2 - m);
  float inv = 1.f / (s0 + s1 + s2);
  mixed[idx] = ((s0 * e0 + s1 * e1 + s2 * e2) * inv + eu) * 0.5f;
}

// out = softmax-weighted(a0,a1,a2) + 0.5*as  (as may alias out; per-element safe)
__global__ __launch_bounds__(256) void final_attn_kernel(
    const float* __restrict__ a0, const float* __restrict__ a1,
    const float* __restrict__ a2, const float* __restrict__ as,
    const float* __restrict__ v, float* __restrict__ out, int nrows) {
  int lane = threadIdx.x & 63;
  int wid = (blockIdx.x * blockDim.x + threadIdx.x) >> 6;
  if (wid >= nrows) return;
  int idx = wid * D + lane;
  float e0 = a0[idx], e1 = a1[idx], e2 = a2[idx], eu = as[idx];
  float vd = v[lane];
  float w0 = wave_sum(e0 * vd);
  float w1 = wave_sum(e1 * vd);
  float w2 = wave_sum(e2 * vd);
  float m = fmaxf(w0, fmaxf(w1, w2));
  float s0 = __expf(w0 - m), s1 = __expf(w1 - m), s2 = __expf(w2 - m);
  float inv = 1.f / (s0 + s1 + s2);
  out[idx] = (s0 * e0 + s1 * e1 + s2 * e2) * inv + 0.5f * eu;
}

// acc += x / max(||x_row||, eps)   (fallback path only)
__global__ __launch_bounds__(256) void l2acc_kernel(const float* __restrict__ x,
                                                    float* __restrict__ acc,
                                                    int nrows) {
  int lane = threadIdx.x & 63;
  int wid = (blockIdx.x * blockDim.x + threadIdx.x) >> 6;
  if (wid >= nrows) return;
  int idx = wid * D + lane;
  float xv = x[idx];
  float ss = wave_sum(xv * xv);
  float nrm = fmaxf(sqrtf(ss), EPS);
  acc[idx] += xv / nrm;
}

// out[row[e], :] += val[e] * x[col[e], :]  (fallback atomic scatter)
__global__ __launch_bounds__(256) void spmm_atomic_kernel(
    const int* __restrict__ row, const int* __restrict__ col,
    const float* __restrict__ val, const float* __restrict__ x,
    float* __restrict__ out, int nnz) {
  int lane = threadIdx.x & 63;
  int wid = (blockIdx.x * blockDim.x + threadIdx.x) >> 6;
  int nw = (gridDim.x * blockDim.x) >> 6;
  for (int base = wid * 64; base < nnz; base += nw * 64) {
    int e = base + lane;
    int r = 0, c = 0;
    float v = 0.f;
    if (e < nnz) { r = row[e]; c = col[e]; v = val[e]; }
    int cnt = nnz - base; if (cnt > 64) cnt = 64;
    for (int i = 0; i < cnt; ++i) {
      int ri = __shfl(r, i, 64);
      int ci = __shfl(c, i, 64);
      float vi = __shfl(v, i, 64);
      float xv = x[ci * D + lane];
      atomicAdd(&out[ri * D + lane], vi * xv);
    }
  }
}

// ---------------- CSR build ----------------

__global__ __launch_bounds__(256) void hist_kernel(const int* __restrict__ row,
                                                   int* __restrict__ counts,
                                                   int nnz) {
  int i = blockIdx.x * blockDim.x + threadIdx.x;
  int n = gridDim.x * blockDim.x;
  for (; i < nnz; i += n) atomicAdd(&counts[row[i]], 1);
}

// per-block exclusive scan of 2048 ints; block totals -> partials
__global__ __launch_bounds__(256) void scan1_kernel(const int* __restrict__ in,
                                                    int* __restrict__ out,
                                                    int* __restrict__ partials,
                                                    int n) {
  __shared__ int lds[256];
  int t = threadIdx.x;
  int base = blockIdx.x * 2048 + t * 8;
  int v[8];
  int s = 0;
#pragma unroll
  for (int k = 0; k < 8; ++k) {
    int i = base + k;
    v[k] = (i < n) ? in[i] : 0;
    s += v[k];
  }
  lds[t] = s;
  __syncthreads();
  for (int ofs = 1; ofs < 256; ofs <<= 1) {
    int add = 0;
    if (t >= ofs) add = lds[t - ofs];
    __syncthreads();
    if (t >= ofs) lds[t] += add;
    __syncthreads();
  }
  int excl = lds[t] - s;
  if (t == 255) partials[blockIdx.x] = lds[255];
  int run = excl;
#pragma unroll
  for (int k = 0; k < 8; ++k) {
    int i = base + k;
    if (i < n) out[i] = run;
    run += v[k];
  }
}

// exclusive scan of P (<=256) partials, in place
__global__ __launch_bounds__(256) void scan2_kernel(int* __restrict__ partials,
                                                    int P) {
  __shared__ int lds[256];
  int t = threadIdx.x;
  int s = (t < P) ? partials[t] : 0;
  lds[t] = s;
  __syncthreads();
  for (int ofs = 1; ofs < 256; ofs <<= 1) {
    int add = 0;
    if (t >= ofs) add = lds[t - ofs];
    __syncthreads();
    if (t >= ofs) lds[t] += add;
    __syncthreads();
  }
  if (t < P) partials[t] = lds[t] - s;
}

__global__ __launch_bounds__(256) void scan3_kernel(
    int* __restrict__ out, const int* __restrict__ partials, int n) {
  int i = blockIdx.x * blockDim.x + threadIdx.x;
  int nt = gridDim.x * blockDim.x;
  for (; i < n; i += nt) out[i] += partials[i >> 11];
}

// ---- chunk-major bucket partition, LDS-sorted (coalesced writes) ----
// Pass 1: per-chunk bucket histogram -> bh[k*nb + b].
__global__ __launch_bounds__(256) void bhist_kernel(
    const int* __restrict__ row, int* __restrict__ bh, int nnz, int nb,
    int chunk) {
  __shared__ int hist[NBMAX];
  for (int i = threadIdx.x; i < nb; i += blockDim.x) hist[i] = 0;
  __syncthreads();
  int base = blockIdx.x * chunk;
  int lim = base + chunk;
  if (lim > nnz) lim = nnz;
  for (int e = base + threadIdx.x; e < lim; e += blockDim.x)
    atomicAdd(&hist[row[e] >> SB], 1);
  __syncthreads();
  int* o = bh + (size_t)blockIdx.x * nb;
  for (int i = threadIdx.x; i < nb; i += blockDim.x) o[i] = hist[i];
}

// Pass 2: per-chunk exclusive scan of its nb counts ->
// fo[k*(nb+1)+b] = k*chunk + excl_prefix ; fo[k*(nb+1)+nb] = chunk end.
__global__ __launch_bounds__(256) void chunkscan_kernel(
    const int* __restrict__ bh, int* __restrict__ fo, int nnz, int nb,
    int chunk) {
  __shared__ int lds[256];
  int k = blockIdx.x;
  int base = k * chunk;
  int t = threadIdx.x;
  const int* in = bh + (size_t)k * nb;
  int v[8];
  int s = 0;
#pragma unroll
  for (int q = 0; q < 8; ++q) {
    int b = t * 8 + q;
    v[q] = (b < nb) ? in[b] : 0;
    s += v[q];
  }
  lds[t] = s;
  __syncthreads();
  for (int ofs = 1; ofs < 256; ofs <<= 1) {
    int add = 0;
    if (t >= ofs) add = lds[t - ofs];
    __syncthreads();
    if (t >= ofs) lds[t] += add;
    __syncthreads();
  }
  int run = base + lds[t] - s;
  int* o = fo + (size_t)k * (nb + 1);
#pragma unroll
  for (int q = 0; q < 8; ++q) {
    int b = t * 8 + q;
    if (b < nb) o[b] = run;
    run += v[q];
  }
  if (t == 255) o[nb] = run;  // = base + edges-in-chunk
}

// Pass 3: LDS counting-sort the chunk's edges by bucket, then write the
// sorted buffer LINEARLY to staging[base..base+cnt) — fully coalesced,
// full-line, compulsory-only writes. (Round-6's direct scatter kept
// single-writer lines but random in-window addresses: partial lines
// evicted ~4x -> 100 MB writes, 146 us. Randomness now confined to LDS.)
__global__ __launch_bounds__(256) void bsort_scatter_kernel(
    const int* __restrict__ row, const int* __restrict__ col,
    const float* __restrict__ val, const int* __restrict__ fo,
    int2* __restrict__ staging, int nnz, int nb, int chunk) {
  __shared__ int cur[NBMAX];
  __shared__ int2 sbuf[CMAX];
  int k = blockIdx.x;
  int base = k * chunk;
  const int* o = fo + (size_t)k * (nb + 1);
  for (int i = threadIdx.x; i < nb; i += blockDim.x) cur[i] = o[i] - base;
  __syncthreads();
  int lim = base + chunk;
  if (lim > nnz) lim = nnz;
  int cnt = lim - base;
  for (int e = base + threadIdx.x; e < lim; e += blockDim.x) {
    int r = row[e];
    int b = r >> SB;
    int idx = atomicAdd(&cur[b], 1);
    sbuf[idx] =
        make_int2(((r & (BSZ - 1)) << 24) | col[e], __float_as_int(val[e]));
  }
  __syncthreads();
  for (int i = threadIdx.x; i < cnt; i += blockDim.x) staging[base + i] = sbuf[i];
}

// Pass 4: one block per bucket; finalize exact CSR order. Fragment
// extents preloaded to LDS in one shot; fragments are tiny (~2 edges at
// NCHUNK=1024) so each THREAD owns fragments (wave-per-fragment would
// idle 62/64 lanes). Row cursors in LDS from row_ptr; writes land in the
// bucket's ~16 KB output region -> L2-absorbed.
__global__ __launch_bounds__(256) void bucket_gather_kernel(
    const int* __restrict__ row_ptr, const int* __restrict__ fo,
    const int2* __restrict__ staging, int2* __restrict__ edges_out, int nrows,
    int nb) {
  __shared__ int lfill[BSZ];
  __shared__ int2 sfrag[NCHUNK];
  int b = blockIdx.x;
  int t = threadIdx.x;
  if (t < BSZ) {
    int r = (b << SB) + t;
    lfill[t] = row_ptr[r < nrows ? r : nrows];
  }
  for (int k = t; k < NCHUNK; k += blockDim.x) {
    const int* o = fo + (size_t)k * (nb + 1) + b;
    sfrag[k] = make_int2(o[0], o[1]);
  }
  __syncthreads();
  for (int k = t; k < NCHUNK; k += blockDim.x) {
    int2 f = sfrag[k];
    for (int e = f.x; e < f.y; ++e) {
      int2 ev = staging[e];
      int lrow = ((unsigned)ev.x) >> 24;
      int idx = atomicAdd(&lfill[lrow], 1);
      edges_out[idx] = make_int2(ev.x & 0xFFFFFF, ev.y);
    }
  }
}

// ---------------- fused CSR SpMM + l2norm-accumulate ----------------
// out[r,:] = sum_e val[e]*x[col[e],:]
// acc[r,:] = (init ? init[r,:] : acc[r,:]) + out[r,:]/max(||out[r,:]||,eps)
// One wave per row; 4-deep gather pipelining.
__global__ __launch_bounds__(256) void spmm_csr_l2acc_kernel(
    const int* __restrict__ row_ptr, const int2* __restrict__ edges,
    const float* __restrict__ x, float* __restrict__ out,
    float* __restrict__ acc, const float* __restrict__ init, int nrows) {
  int lane = threadIdx.x & 63;
  int r = (blockIdx.x * blockDim.x + threadIdx.x) >> 6;
  if (r >= nrows) return;
  int start = row_ptr[r], end = row_ptr[r + 1];
  float sum = 0.f;
  for (int j = start; j < end; j += 64) {
    int e = j + lane;
    int c = 0;
    float v = 0.f;
    if (e < end) {
      int2 ev = edges[e];
      c = ev.x;
      v = __int_as_float(ev.y);
    }
    int cnt = end - j;
    if (cnt > 64) cnt = 64;
    int i = 0;
    for (; i + 4 <= cnt; i += 4) {
      int c0 = __shfl(c, i, 64);
      int c1 = __shfl(c, i + 1, 64);
      int c2 = __shfl(c, i + 2, 64);
      int c3 = __shfl(c, i + 3, 64);
      float v0 = __shfl(v, i, 64);
      float v1 = __shfl(v, i + 1, 64);
      float v2 = __shfl(v, i + 2, 64);
      float v3 = __shfl(v, i + 3, 64);
      float x0 = x[c0 * D + lane];
      float x1 = x[c1 * D + lane];
      float x2 = x[c2 * D + lane];
      float x3 = x[c3 * D + lane];
      sum += v0 * x0;
      sum += v1 * x1;
      sum += v2 * x2;
      sum += v3 * x3;
    }
    for (; i < cnt; ++i) {
      int ci = __shfl(c, i, 64);
      float vi = __shfl(v, i, 64);
      sum += vi * x[ci * D + lane];
    }
  }
  int idx = r * D + lane;
  out[idx] = sum;
  float ss = wave_sum(sum * sum);
  float nrm = fmaxf(sqrtf(ss), EPS);
  float base = init ? init[idx] : acc[idx];
  acc[idx] = base + sum / nrm;
}

// ---------------- host ----------------

static void build_csr(const int* row, const int* col, const float* val, int nnz,
                      int nrows, int* counts, int* row_ptr, int* partials,
                      int* bh, int* fo, int2* staging, int2* edges_out,
                      hipStream_t stream) {
  int n1 = nrows + 1;
  hipMemsetAsync(counts, 0, n1 * sizeof(int), stream);
  hipLaunchKernelGGL(hist_kernel, dim3(1024), dim3(256), 0, stream, row, counts,
                     nnz);
  int nblk = (n1 + 2047) / 2048;
  hipLaunchKernelGGL(scan1_kernel, dim3(nblk), dim3(256), 0, stream, counts,
                     row_ptr, partials, n1);
  hipLaunchKernelGGL(scan2_kernel, dim3(1), dim3(256), 0, stream, partials,
                     nblk);
  hipLaunchKernelGGL(scan3_kernel, dim3(64), dim3(256), 0, stream, row_ptr,
                     partials, n1);
  int nb = (nrows + BSZ - 1) >> SB;
  int chunk = (nnz + NCHUNK - 1) / NCHUNK;
  hipLaunchKernelGGL(bhist_kernel, dim3(NCHUNK), dim3(256), 0, stream, row, bh,
                     nnz, nb, chunk);
  hipLaunchKernelGGL(chunkscan_kernel, dim3(NCHUNK), dim3(256), 0, stream, bh,
                     fo, nnz, nb, chunk);
  hipLaunchKernelGGL(bsort_scatter_kernel, dim3(NCHUNK), dim3(256), 0, stream,
                     row, col, val, fo, staging, nnz, nb, chunk);
  hipLaunchKernelGGL(bucket_gather_kernel, dim3(nb), dim3(256), 0, stream,
                     row_ptr, fo, staging, edges_out, nrows, nb);
}

extern "C" void kernel_launch(void* const* d_in, const int* in_sizes, int n_in,
                              void* d_out, int out_size, void* d_ws,
                              size_t ws_size, hipStream_t stream) {
  const float* user_emb = (const float*)d_in[0];
  const float* item_emb = (const float*)d_in[1];
  const float* gating_w = (const float*)d_in[2];
  const float* gating_b = (const float*)d_in[3];
  const float* sgating_w = (const float*)d_in[4];
  const float* sgating_b = (const float*)d_in[5];
  const float* att_mat = (const float*)d_in[6];
  const float* att_agg = (const float*)d_in[7];
  const int* hs_row = (const int*)d_in[8];
  const int* hs_col = (const int*)d_in[9];
  const float* hs_val = (const float*)d_in[10];
  const int* hj_row = (const int*)d_in[11];
  const int* hj_col = (const int*)d_in[12];
  const float* hj_val = (const float*)d_in[13];
  const int* hp_row = (const int*)d_in[14];
  const int* hp_col = (const int*)d_in[15];
  const float* hp_val = (const float*)d_in[16];
  const int* inter_row = (const int*)d_in[17];
  const int* inter_col = (const int*)d_in[18];
  const float* inter_val = (const float*)d_in[19];

  const int U = in_sizes[0] / D;  // 100000
  const int I = in_sizes[1] / D;  // 50000
  const int NH = in_sizes[8];     // 3200000
  const int NI = in_sizes[17];    // 3000000
  const size_t UD = (size_t)U * D;
  const size_t ID = (size_t)I * D;

  float* out = (float*)d_out;
  float* final_user = out;  // also acc_simple storage
  float* acc_item = out + UD;
  float* sg0 = out + UD + ID;  // also acc_c0
  float* sg1 = sg0 + UD;       // also acc_c1
  float* sg2 = sg1 + UD;       // also acc_c2
  float* acc0 = sg0, *acc1 = sg1, *acc2 = sg2, *accS = final_user;

  // ---- workspace bump allocator ----
  char* p = (char*)d_ws;
  auto alloc = [&](size_t bytes) -> void* {
    void* r = (void*)p;
    p += (bytes + 255) & ~(size_t)255;
    return r;
  };
  float* u0 = (float*)alloc(UD * 4);
  float* u1 = (float*)alloc(UD * 4);
  float* u2 = (float*)alloc(UD * 4);
  float* us = (float*)alloc(UD * 4);
  float* mixed = (float*)alloc(UD * 4);
  float* spare = (float*)alloc(UD * 4);
  float* it_a = (float*)alloc(ID * 4);
  float* it_b = (float*)alloc(ID * 4);
  float* v = (float*)alloc(256 * 4);
  int* partials = (int*)alloc(256 * 4);
  // CSR structures
  int* cnt_u = (int*)alloc((U + 2) * 4);  // shared counts buffer (user)
  int* cnt_i = (int*)alloc((I + 2) * 4);  // (item)
  const int NB_U = (U + BSZ - 1) >> SB;
  const int NB_I = (I + BSZ - 1) >> SB;
  const int NB_MAXU = (NB_U > NB_I ? NB_U : NB_I);
  int* fo = (int*)alloc((size_t)NCHUNK * (NB_MAXU + 1) * 4);  // transient
  int* rp_hs = (int*)alloc((U + 2) * 4);
  int* rp_hj = (int*)alloc((U + 2) * 4);
  int* rp_hp = (int*)alloc((U + 2) * 4);
  int* rp_iu = (int*)alloc((U + 2) * 4);
  int* rp_ii = (int*)alloc((I + 2) * 4);
  // staging is only live inside build_csr; spare is first written after
  // all builds complete (in-order stream) -> alias when it fits.
  size_t NMAX = (size_t)(NH > NI ? NH : NI);
  int2* staging;
  if (NMAX * 8 <= UD * 4) staging = (int2*)spare;
  else staging = (int2*)alloc(NMAX * 8);
  int2* ed_hs = (int2*)alloc((size_t)NH * 8);
  int2* ed_hj = (int2*)alloc((size_t)NH * 8);
  int2* ed_hp = (int2*)alloc((size_t)NH * 8);
  int2* ed_iu = (int2*)alloc((size_t)NI * 8);
  int2* ed_ii = (int2*)alloc((size_t)NI * 8);
  // bh is dead after each build's chunkscan, and ed_ii is only written in
  // build 5's bucket_gather (after its chunkscan) -> alias bh into ed_ii.
  int* bh = (int*)ed_ii;
  bool bh_fits = (size_t)NCHUNK * NB_MAXU * 4 <= (size_t)NI * 8;
  size_t needed = (size_t)(p - (char*)d_ws);
  // CSR path: cols fit 24-bit packed field, buckets fit NBMAX, chunks fit CMAX
  bool use_csr = needed <= ws_size && U < (1 << 24) && I < (1 << 24) &&
                 U <= NBMAX * BSZ && I <= NBMAX * BSZ && bh_fits &&
                 NH <= NCHUNK * CMAX && NI <= NCHUNK * CMAX;

  const int ROWB_U = (U + 3) / 4;  // wave-per-row blocks (256 thr = 4 waves)
  const int ROWB_I = (I + 3) / 4;
  const int SPMM_BLOCKS = 2048;

  // v = att_mat @ att_agg^T
  hipLaunchKernelGGL(compute_v_kernel, dim3(1), dim3(64), 0, stream, att_mat,
                     att_agg, v);
  // self-gating (4 channels); acc copies only needed on fallback path
  hipLaunchKernelGGL(gating4_kernel, dim3(512), dim3(256), 0, stream, user_emb,
                     gating_w, gating_b, u0, u1, u2, us,
                     use_csr ? (float*)nullptr : acc0,
                     use_csr ? (float*)nullptr : acc1,
                     use_csr ? (float*)nullptr : acc2,
                     use_csr ? (float*)nullptr : accS, U);
  if (!use_csr) {
    hipMemcpyAsync(acc_item, item_emb, ID * sizeof(float),
                   hipMemcpyDeviceToDevice, stream);
    hipMemcpyAsync(it_a, item_emb, ID * sizeof(float), hipMemcpyDeviceToDevice,
                   stream);
  }

  if (use_csr) {
    build_csr(hs_row, hs_col, hs_val, NH, U, cnt_u, rp_hs, partials, bh, fo,
              staging, ed_hs, stream);
    build_csr(hj_row, hj_col, hj_val, NH, U, cnt_u, rp_hj, partials, bh, fo,
              staging, ed_hj, stream);
    build_csr(hp_row, hp_col, hp_val, NH, U, cnt_u, rp_hp, partials, bh, fo,
              staging, ed_hp, stream);
    build_csr(inter_row, inter_col, inter_val, NI, U, cnt_u, rp_iu, partials,
              bh, fo, staging, ed_iu, stream);
    build_csr(inter_col, inter_row, inter_val, NI, I, cnt_i, rp_ii, partials,
              bh, fo, staging, ed_ii, stream);
  }

  // CSR path: layer-0 item source is item_emb directly (no it_a copy)
  const float* it_src = item_emb;
  float* it_dst = it_b;
  // fallback path pointers
  float* it_old = it_a;
  float* it_new = it_b;

  for (int layer = 0; layer < 2; ++layer) {
    hipLaunchKernelGGL(attn_mix_kernel, dim3(ROWB_U), dim3(256), 0, stream, u0,
                       u1, u2, us, v, mixed, U);
    if (use_csr) {
      const float* i0 = (layer == 0) ? u0 : nullptr;
      const float* i1 = (layer == 0) ? u1 : nullptr;
      const float* i2 = (layer == 0) ? u2 : nullptr;
      const float* ii = (layer == 0) ? item_emb : nullptr;
      const float* is = (layer == 0) ? us : nullptr;
      hipLaunchKernelGGL(spmm_csr_l2acc_kernel, dim3(ROWB_U), dim3(256), 0,
                         stream, rp_hs, ed_hs, u0, spare, acc0, i0, U);
      { float* t = u0; u0 = spare; spare = t; }
      hipLaunchKernelGGL(spmm_csr_l2acc_kernel, dim3(ROWB_U), dim3(256), 0,
                         stream, rp_hj, ed_hj, u1, spare, acc1, i1, U);
      { float* t = u1; u1 = spare; spare = t; }
      hipLaunchKernelGGL(spmm_csr_l2acc_kernel, dim3(ROWB_U), dim3(256), 0,
                         stream, rp_hp, ed_hp, u2, spare, acc2, i2, U);
      { float* t = u2; u2 = spare; spare = t; }
      hipLaunchKernelGGL(spmm_csr_l2acc_kernel, dim3(ROWB_I), dim3(256), 0,
                         stream, rp_ii, ed_ii, mixed, it_dst, acc_item, ii, I);
      hipLaunchKernelGGL(spmm_csr_l2acc_kernel, dim3(ROWB_U), dim3(256), 0,
                         stream, rp_iu, ed_iu, it_src, spare, accS, is, U);
      { float* t = us; us = spare; spare = t; }
      it_src = it_dst;
      it_dst = it_a;
    } else {
      hipMemsetAsync(spare, 0, UD * sizeof(float), stream);
      hipLaunchKernelGGL(spmm_atomic_kernel, dim3(SPMM_BLOCKS), dim3(256), 0,
                         stream, hs_row, hs_col, hs_val, u0, spare, NH);
      hipLaunchKernelGGL(l2acc_kernel, dim3(ROWB_U), dim3(256), 0, stream,
                         spare, acc0, U);
      { float* t = u0; u0 = spare; spare = t; }
      hipMemsetAsync(spare, 0, UD * sizeof(float), stream);
      hipLaunchKernelGGL(spmm_atomic_kernel, dim3(SPMM_BLOCKS), dim3(256), 0,
                         stream, hj_row, hj_col, hj_val, u1, spare, NH);
      hipLaunchKernelGGL(l2acc_kernel, dim3(ROWB_U), dim3(256), 0, stream,
                         spare, acc1, U);
      { float* t = u1; u1 = spare; spare = t; }
      hipMemsetAsync(spare, 0, UD * sizeof(float), stream);
      hipLaunchKernelGGL(spmm_atomic_kernel, dim3(SPMM_BLOCKS), dim3(256), 0,
                         stream, hp_row, hp_col, hp_val, u2, spare, NH);
      hipLaunchKernelGGL(l2acc_kernel, dim3(ROWB_U), dim3(256), 0, stream,
                         spare, acc2, U);
      { float* t = u2; u2 = spare; spare = t; }
      hipMemsetAsync(it_new, 0, ID * sizeof(float), stream);
      hipLaunchKernelGGL(spmm_atomic_kernel, dim3(SPMM_BLOCKS), dim3(256), 0,
                         stream, inter_col, inter_row, inter_val, mixed, it_new,
                         NI);
      hipLaunchKernelGGL(l2acc_kernel, dim3(ROWB_I), dim3(256), 0, stream,
                         it_new, acc_item, I);
      hipMemsetAsync(spare, 0, UD * sizeof(float), stream);
      hipLaunchKernelGGL(spmm_atomic_kernel, dim3(SPMM_BLOCKS), dim3(256), 0,
                         stream, inter_row, inter_col, inter_val, it_old, spare,
                         NI);
      hipLaunchKernelGGL(l2acc_kernel, dim3(ROWB_U), dim3(256), 0, stream,
                         spare, accS, U);
      { float* t = us; us = spare; spare = t; }
      { float* t = it_old; it_old = it_new; it_new = t; }
    }
  }

  hipLaunchKernelGGL(final_attn_kernel, dim3(ROWB_U), dim3(256), 0, stream,
                     acc0, acc1, acc2, accS, v, final_user, U);
  hipLaunchKernelGGL(sgating3_kernel, dim3(512), dim3(256), 0, stream,
                     final_user, sgating_w, sgating_b, sg0, sg1, sg2, U);
}